// Round 8
// baseline (668.165 us; speedup 1.0000x reference)
//
#include <hip/hip_runtime.h>
#include <hip/hip_bf16.h>
#include <stdint.h>

#define N_NODES 50000
#define N_EDGES 1600000
#define D_IN    512
#define D_H1    256   // 4 heads * 64 concat
#define D_OUT   64

#define NBUK    196   // coarse buckets: src>>8 (256 nodes each)
#define MAXB    9216  // per-bucket region capacity (mean 8163, +11 sigma)
#define EPB     4096  // edges per partition block
#define NPB     391   // ceil(N_EDGES / EPB)
#define SLOT    96    // per-node list stride (max degree ~58 for Poisson(32))

// phased agg1: 896 co-resident blocks, half-wave owns a node, 7 nodes per half-wave
#define AGB     896
#define NSN     7     // 896 blocks * 8 half-waves * 7 = 50176 >= 50000
#define RR      25    // dst ranges of 2048 rows (1 MB t1 slice each)

typedef __attribute__((ext_vector_type(8))) short  short8;   // 8 bf16 = 4 VGPRs (MFMA A/B frag)
typedef __attribute__((ext_vector_type(4))) float  f32x4;    // MFMA C/D frag
typedef __attribute__((ext_vector_type(4))) unsigned int u32x4;
typedef __attribute__((ext_vector_type(2))) unsigned int u32x2;

static __device__ __forceinline__ unsigned short f2bf(float f) {
    union { float f; unsigned int u; } c; c.f = f;
    unsigned int u = c.u;
    return (unsigned short)((u + 0x7FFFu + ((u >> 16) & 1u)) >> 16);  // RNE
}
static __device__ __forceinline__ float bf2f(unsigned short b) {
    union { unsigned int u; float f; } c; c.u = ((unsigned int)b) << 16;
    return c.f;
}
static __device__ __forceinline__ float bflo(unsigned int v) { return bf2f((unsigned short)(v & 0xffffu)); }
static __device__ __forceinline__ float bfhi(unsigned int v) { return bf2f((unsigned short)(v >> 16)); }

// ---------------- phase 1: partition edges into 196 coarse buckets ----------------
// All global writes are run-contiguous (LDS-staged): ~11 MB of line traffic vs the
// ~102 MB a naive per-edge random scatter costs (R5/R6 measured).

__global__ __launch_bounds__(256) void part_kernel(const int* __restrict__ src,
                                                   const int* __restrict__ dst,
                                                   int* __restrict__ gcnt,
                                                   unsigned int* __restrict__ gbuk) {
    __shared__ int hist[NBUK];
    __shared__ int lofs[NBUK];          // exclusive offsets in sorted[]
    __shared__ int gbase[NBUK];         // this block's reservation in bucket region
    __shared__ int sbuf[256];
    __shared__ unsigned int sorted[EPB];
    __shared__ unsigned char bid[EPB];

    const int t  = threadIdx.x;
    const int e0 = blockIdx.x * EPB;
    int ec = N_EDGES - e0; if (ec > EPB) ec = EPB;

    for (int i = t; i < NBUK; i += 256) hist[i] = 0;
    __syncthreads();

    unsigned int rec[16];
    int bb[16], idx[16];
#pragma unroll
    for (int j = 0; j < 16; ++j) {
        int i = j * 256 + t;
        if (i < ec) {
            int s = src[e0 + i], d = dst[e0 + i];
            int b = s >> 8;
            rec[j] = ((unsigned int)(s & 255) << 16) | (unsigned int)d;
            bb[j]  = b;
            idx[j] = atomicAdd(&hist[b], 1);
        } else bb[j] = -1;
    }
    __syncthreads();

    // inclusive scan of hist over 256 slots (entries >= NBUK are 0)
    int v = (t < NBUK) ? hist[t] : 0;
    sbuf[t] = v;
    __syncthreads();
#pragma unroll
    for (int off = 1; off < 256; off <<= 1) {
        int x = (t >= off) ? sbuf[t - off] : 0;
        __syncthreads();
        sbuf[t] += x;
        __syncthreads();
    }
    if (t < NBUK) {
        lofs[t]  = sbuf[t] - v;                 // exclusive
        gbase[t] = atomicAdd(&gcnt[t], v);      // one global atomic per bucket per block
    }
    __syncthreads();

#pragma unroll
    for (int j = 0; j < 16; ++j) {
        if (bb[j] >= 0) {
            int p = lofs[bb[j]] + idx[j];
            sorted[p] = rec[j];
            bid[p] = (unsigned char)bb[j];
        }
    }
    __syncthreads();

    for (int i = t; i < ec; i += 256) {
        int b = bid[i];
        int p = gbase[b] + (i - lofs[b]);
        gbuk[(size_t)b * MAXB + p] = sorted[i];
    }
}

// ---------------- phase 2: per-bucket counting sort -> per-node DST-SORTED lists ----------------

__global__ __launch_bounds__(256) void sort_kernel(const int* __restrict__ gcnt,
                                                   const unsigned int* __restrict__ gbuk,
                                                   unsigned short* __restrict__ sdst,
                                                   int* __restrict__ deg) {
    __shared__ int hist[256];
    __shared__ int nofs[256];           // exclusive offsets, used as running cursors
    __shared__ int sbuf[256];
    __shared__ unsigned short list[MAXB];

    const int t = threadIdx.x;
    const int b = blockIdx.x;
    const int cnt = gcnt[b];
    const unsigned int* buk = gbuk + (size_t)b * MAXB;

    hist[t] = 0;
    __syncthreads();
    for (int i = t; i < cnt; i += 256)
        atomicAdd(&hist[buk[i] >> 16], 1);
    __syncthreads();

    int v = hist[t];
    sbuf[t] = v;
    __syncthreads();
#pragma unroll
    for (int off = 1; off < 256; off <<= 1) {
        int x = (t >= off) ? sbuf[t - off] : 0;
        __syncthreads();
        sbuf[t] += x;
        __syncthreads();
    }
    nofs[t] = sbuf[t] - v;              // exclusive
    const int n = b * 256 + t;
    if (n < N_NODES) deg[n] = v;
    __syncthreads();

    for (int i = t; i < cnt; i += 256) {
        unsigned int r = buk[i];
        int p = atomicAdd(&nofs[r >> 16], 1);
        list[p] = (unsigned short)(r & 0xffffu);
    }
    __syncthreads();

    // insertion-sort this node's slice by dst (enables agg1's range-phase sweep)
    const int endp = nofs[t];           // inclusive end
    const int beg  = endp - v;
    for (int j = beg + 1; j < endp; ++j) {
        unsigned short key = list[j];
        int k = j - 1;
        while (k >= beg && list[k] > key) { list[k + 1] = list[k]; --k; }
        list[k + 1] = key;
    }
    __syncthreads();

    if (n < N_NODES && v > 0) {
        unsigned short* out = sdst + (size_t)n * SLOT;
        for (int j = 0; j < v; ++j) out[j] = list[beg + j];
    }
}

// ---------------- weight repack (fused, fp32 -> bf16, B transposed: [n][k]) ----------------

__global__ void convw_kernel(const float* __restrict__ W1, const float* __restrict__ W2,
                             unsigned short* __restrict__ Bt1, unsigned short* __restrict__ Bt2) {
    int i = blockIdx.x * 256 + threadIdx.x;
    if (i < 4 * 512 * 64) {                 // W1[h][k][j] -> Bt1[(h*64+j)][k]
        int h = i >> 15;
        int k = (i >> 6) & 511;
        int j = i & 63;
        Bt1[(h * 64 + j) * 512 + k] = f2bf(W1[i]);
    } else {
        int r = i - 4 * 512 * 64;           // W2[k][n] -> Bt2[n][k]
        if (r < 256 * 64) {
            int k = r >> 6;
            int n = r & 63;
            Bt2[n * 256 + k] = f2bf(W2[r]);
        }
    }
}

// ---------------- GEMM1: t1[M][256] = X[M][512](fp32, staged->bf16) @ Bt1[256][512]^T ----------------
// BM=128, BN=256 (A read once), block=512 (8 waves 2x4), wave tile 64x64, BK=32.

__global__ __launch_bounds__(512) void gemm1_kernel(const float* __restrict__ A,
                                                    const unsigned short* __restrict__ Bt,
                                                    unsigned short* __restrict__ C) {
    constexpr int BM = 128, BN = 256, BK = 32, LDK = 40, K = D_IN, M = N_NODES, N = D_H1;
    __shared__ unsigned short As[BM * LDK];   // 10.0 KB
    __shared__ unsigned short Bs[BN * LDK];   // 20.0 KB

    const int tid  = threadIdx.x;
    const int lane = tid & 63;
    const int w    = tid >> 6;
    const int wm   = (w >> 2) * 64;
    const int wn   = (w & 3) * 64;
    const int quad = lane >> 4;
    const int l15  = lane & 15;
    const int bm   = blockIdx.x;

    f32x4 acc[4][4];
#pragma unroll
    for (int mi = 0; mi < 4; ++mi)
#pragma unroll
        for (int ni = 0; ni < 4; ++ni)
            acc[mi][ni] = (f32x4){0.f, 0.f, 0.f, 0.f};

    const int r0 = tid >> 2;      // 0..127
    const int f8 = tid & 3;       // 8-elem chunk within a 32-col row

    for (int k0 = 0; k0 < K; k0 += BK) {
        {   // stage A (128 x 32 fp32 -> bf16), 8 floats per thread
            int grow = bm * BM + r0;
            if (grow >= M) grow = M - 1;
            const float* ap = A + (size_t)grow * K + k0 + f8 * 8;
            f32x4 v0 = *(const f32x4*)ap;
            f32x4 v1 = *(const f32x4*)(ap + 4);
            u32x4 pk;
            pk[0] = (unsigned int)f2bf(v0[0]) | ((unsigned int)f2bf(v0[1]) << 16);
            pk[1] = (unsigned int)f2bf(v0[2]) | ((unsigned int)f2bf(v0[3]) << 16);
            pk[2] = (unsigned int)f2bf(v1[0]) | ((unsigned int)f2bf(v1[1]) << 16);
            pk[3] = (unsigned int)f2bf(v1[2]) | ((unsigned int)f2bf(v1[3]) << 16);
            *(u32x4*)&As[r0 * LDK + f8 * 8] = pk;
        }
        {   // stage B (256 x 32 bf16), two u32x4 per thread
#pragma unroll
            for (int p = 0; p < 2; ++p) {
                int row = p * 128 + r0;
                u32x4 v = *(const u32x4*)(Bt + (size_t)row * K + k0 + f8 * 8);
                *(u32x4*)&Bs[row * LDK + f8 * 8] = v;
            }
        }
        __syncthreads();

        short8 af[4], bfr[4];
#pragma unroll
        for (int mi = 0; mi < 4; ++mi)
            af[mi] = *(const short8*)&As[(wm + mi * 16 + l15) * LDK + quad * 8];
#pragma unroll
        for (int ni = 0; ni < 4; ++ni)
            bfr[ni] = *(const short8*)&Bs[(wn + ni * 16 + l15) * LDK + quad * 8];
#pragma unroll
        for (int mi = 0; mi < 4; ++mi)
#pragma unroll
            for (int ni = 0; ni < 4; ++ni)
                acc[mi][ni] = __builtin_amdgcn_mfma_f32_16x16x32_bf16(af[mi], bfr[ni], acc[mi][ni], 0, 0, 0);
        __syncthreads();
    }

#pragma unroll
    for (int mi = 0; mi < 4; ++mi) {
        int row0 = bm * BM + wm + mi * 16 + quad * 4;
#pragma unroll
        for (int ni = 0; ni < 4; ++ni) {
            int col = wn + ni * 16 + l15;
#pragma unroll
            for (int r = 0; r < 4; ++r) {
                int row = row0 + r;
                if (row < M) C[(size_t)row * N + col] = f2bf(acc[mi][ni][r]);
            }
        }
    }
}

// ---------------- GEMM2: t2[M][64] = h[M][256](bf16) @ Bt2[64][256]^T ----------------

__global__ __launch_bounds__(256) void gemm2_kernel(const unsigned short* __restrict__ A,
                                                    const unsigned short* __restrict__ Bt,
                                                    unsigned short* __restrict__ C) {
    constexpr int BM = 64, BN = 64, BK = 32, LDK = 40, K = D_H1, M = N_NODES, N = D_OUT;
    __shared__ unsigned short As[BM * LDK];
    __shared__ unsigned short Bs[BN * LDK];

    const int tid  = threadIdx.x;
    const int lane = tid & 63;
    const int w    = tid >> 6;
    const int wm   = (w >> 1) * 32;
    const int wn   = (w & 1) * 32;
    const int quad = lane >> 4;
    const int l15  = lane & 15;
    const int bm   = blockIdx.x;

    f32x4 acc[2][2];
#pragma unroll
    for (int mi = 0; mi < 2; ++mi)
#pragma unroll
        for (int ni = 0; ni < 2; ++ni)
            acc[mi][ni] = (f32x4){0.f, 0.f, 0.f, 0.f};

    for (int k0 = 0; k0 < K; k0 += BK) {
        {
            int f8 = tid & 3;
            int r0 = tid >> 2;
            int grow = bm * BM + r0;
            if (grow >= M) grow = M - 1;
            u32x4 v = *(const u32x4*)(A + (size_t)grow * K + k0 + f8 * 8);
            *(u32x4*)&As[r0 * LDK + f8 * 8] = v;
        }
        {
            int f8 = tid & 3;
            int r0 = tid >> 2;
            u32x4 v = *(const u32x4*)(Bt + (size_t)r0 * K + k0 + f8 * 8);
            *(u32x4*)&Bs[r0 * LDK + f8 * 8] = v;
        }
        __syncthreads();

        short8 af[2], bfr[2];
#pragma unroll
        for (int mi = 0; mi < 2; ++mi)
            af[mi] = *(const short8*)&As[(wm + mi * 16 + l15) * LDK + quad * 8];
#pragma unroll
        for (int ni = 0; ni < 2; ++ni)
            bfr[ni] = *(const short8*)&Bs[(wn + ni * 16 + l15) * LDK + quad * 8];
#pragma unroll
        for (int mi = 0; mi < 2; ++mi)
#pragma unroll
            for (int ni = 0; ni < 2; ++ni)
                acc[mi][ni] = __builtin_amdgcn_mfma_f32_16x16x32_bf16(af[mi], bfr[ni], acc[mi][ni], 0, 0, 0);
        __syncthreads();
    }

#pragma unroll
    for (int mi = 0; mi < 2; ++mi) {
        int row0 = bm * BM + wm + mi * 16 + quad * 4;
#pragma unroll
        for (int ni = 0; ni < 2; ++ni) {
            int col = wn + ni * 16 + l15;
#pragma unroll
            for (int r = 0; r < 4; ++r) {
                int row = row0 + r;
                if (row < M) C[(size_t)row * N + col] = f2bf(acc[mi][ni][r]);
            }
        }
    }
}

// ---------------- aggregation 1: phased dst-range sweep (R4 locality, R7 execution) ----------------
// 896 co-resident blocks (4/CU), half-wave (32 lanes x 16B = 512B row) owns a node,
// NSN=7 nodes per half-wave, acc[7][8] in VGPRs. Outer loop over 25 dst-ranges; lists
// are dst-sorted so each range's edges are a prefix-run found by el[e] < hi.
// Per-range __syncthreads keeps the block's 8 half-waves in phase; co-residency +
// equal work keeps blocks roughly aligned (per-XCD L2 holds ~4 slices of slack).

__global__ __launch_bounds__(256, 4) void agg1_kernel(const unsigned short* __restrict__ t,
                                                      const int* __restrict__ deg,
                                                      const unsigned short* __restrict__ sdst,
                                                      unsigned short* __restrict__ h) {
    const int w    = threadIdx.x >> 6;
    const int lane = threadIdx.x & 63;
    const int hs   = lane >> 5;          // half-wave select
    const int c    = lane & 31;          // cols 8c..8c+7
    const int half_id = (blockIdx.x * 4 + w) * 2 + hs;
    const int s0 = half_id * NSN;
    const unsigned short* base = t + 8 * c;

    float acc[NSN][8];
    int   cur[NSN], dg[NSN];
#pragma unroll
    for (int i = 0; i < NSN; ++i) {
        int s = s0 + i;
        dg[i] = (s < N_NODES) ? deg[s] : 0;
        cur[i] = 0;
#pragma unroll
        for (int k = 0; k < 8; ++k) acc[i][k] = 0.f;
    }

    for (int r = 0; r < RR; ++r) {
        const int hi = (r == RR - 1) ? 65536 : ((r + 1) << 11);
#pragma unroll
        for (int i = 0; i < NSN; ++i) {
            const unsigned short* el = sdst + (size_t)(s0 + i) * SLOT;
            int e = cur[i];
            const int d = dg[i];
            while (e < d) {
                int idx = el[e];
                if (idx >= hi) break;
                u32x4 v = *(const u32x4*)(base + (size_t)idx * D_H1);
                acc[i][0] += bflo(v[0]); acc[i][1] += bfhi(v[0]);
                acc[i][2] += bflo(v[1]); acc[i][3] += bfhi(v[1]);
                acc[i][4] += bflo(v[2]); acc[i][5] += bfhi(v[2]);
                acc[i][6] += bflo(v[3]); acc[i][7] += bfhi(v[3]);
                ++e;
            }
            cur[i] = e;
        }
        __syncthreads();   // keep the block's half-waves sweeping the same slice
    }

#pragma unroll
    for (int i = 0; i < NSN; ++i) {
        int s = s0 + i;
        if (s < N_NODES) {
            float iv = (dg[i] > 0) ? (1.0f / (float)dg[i]) : 0.f;
            u32x4 pk;
#pragma unroll
            for (int q = 0; q < 4; ++q) {
                float m0 = acc[i][2 * q] * iv, m1 = acc[i][2 * q + 1] * iv;
                m0 = (m0 > 0.f) ? m0 : (__expf(m0) - 1.f);
                m1 = (m1 > 0.f) ? m1 : (__expf(m1) - 1.f);
                pk[q] = (unsigned int)f2bf(m0) | ((unsigned int)f2bf(m1) << 16);
            }
            *(u32x4*)&h[(size_t)s * D_H1 + 8 * c] = pk;
        }
    }
}

// ---------------- aggregation 2: one wave per node, quarter-wave x 4 edges ----------------

__global__ __launch_bounds__(256) void agg2_kernel(const unsigned short* __restrict__ t2,
                                                   const int* __restrict__ deg,
                                                   const unsigned short* __restrict__ sdst,
                                                   float* __restrict__ out) {
    int s = __builtin_amdgcn_readfirstlane(blockIdx.x * 4 + (threadIdx.x >> 6));
    int lane = threadIdx.x & 63;
    int sub = lane >> 4;         // which of 4 concurrent edges
    int c   = lane & 15;         // 4 cols per lane: 4c..4c+3
    int end = deg[s];
    const unsigned short* el = sdst + (size_t)s * SLOT;
    const unsigned short* bb = t2 + 4 * c;

    float a0 = 0.f, a1 = 0.f, a2 = 0.f, a3 = 0.f;
    int e = 0;
    for (; e + 8 <= end; e += 8) {
        int i0 = el[e + sub], i1 = el[e + 4 + sub];
        u32x2 v0 = *(const u32x2*)(bb + (size_t)i0 * D_OUT);
        u32x2 v1 = *(const u32x2*)(bb + (size_t)i1 * D_OUT);
        a0 += bflo(v0[0]) + bflo(v1[0]);
        a1 += bfhi(v0[0]) + bfhi(v1[0]);
        a2 += bflo(v0[1]) + bflo(v1[1]);
        a3 += bfhi(v0[1]) + bfhi(v1[1]);
    }
    for (; e + 4 <= end; e += 4) {
        int i0 = el[e + sub];
        u32x2 v = *(const u32x2*)(bb + (size_t)i0 * D_OUT);
        a0 += bflo(v[0]); a1 += bfhi(v[0]); a2 += bflo(v[1]); a3 += bfhi(v[1]);
    }
    int rem = end - e;
    if (sub < rem) {
        int i0 = el[e + sub];
        u32x2 v = *(const u32x2*)(bb + (size_t)i0 * D_OUT);
        a0 += bflo(v[0]); a1 += bfhi(v[0]); a2 += bflo(v[1]); a3 += bfhi(v[1]);
    }
    a0 += __shfl_xor(a0, 16); a1 += __shfl_xor(a1, 16);
    a2 += __shfl_xor(a2, 16); a3 += __shfl_xor(a3, 16);
    a0 += __shfl_xor(a0, 32); a1 += __shfl_xor(a1, 32);
    a2 += __shfl_xor(a2, 32); a3 += __shfl_xor(a3, 32);
    if (sub == 0) {
        float iv = (end > 0) ? (1.0f / (float)end) : 0.f;
        f32x4 r; r[0] = a0 * iv; r[1] = a1 * iv; r[2] = a2 * iv; r[3] = a3 * iv;
        *(f32x4*)(out + (size_t)s * D_OUT + 4 * c) = r;
    }
}

// ---------------- launch ----------------

extern "C" void kernel_launch(void* const* d_in, const int* in_sizes, int n_in,
                              void* d_out, int out_size, void* d_ws, size_t ws_size,
                              hipStream_t stream) {
    const float* X  = (const float*)d_in[0];
    const int*   ei = (const int*)d_in[1];
    const float* W1 = (const float*)d_in[2];
    const float* W2 = (const float*)d_in[3];
    const int* src = ei;             // edge_index[0] = segment ids
    const int* dst = ei + N_EDGES;   // edge_index[1] = gathered neighbors

    char* ws = (char*)d_ws;
    size_t off = 0;
    auto alloc = [&](size_t bytes) {
        off = (off + 255) & ~(size_t)255;
        void* p = ws + off;
        off += bytes;
        return p;
    };
    int*          gcnt = (int*)alloc((size_t)NBUK * 4);
    unsigned int* gbuk = (unsigned int*)alloc((size_t)NBUK * MAXB * 4);
    unsigned short* sdst = (unsigned short*)alloc(((size_t)(N_NODES + NSN * 16) * SLOT) * 2);
    int*          deg  = (int*)alloc((size_t)N_NODES * 4);
    unsigned short* Bt1 = (unsigned short*)alloc((size_t)D_H1 * D_IN * 2);
    unsigned short* Bt2 = (unsigned short*)alloc((size_t)D_OUT * D_H1 * 2);
    unsigned short* t1  = (unsigned short*)alloc((size_t)N_NODES * D_H1 * 2);
    unsigned short* h   = (unsigned short*)alloc((size_t)N_NODES * D_H1 * 2);
    unsigned short* t2  = (unsigned short*)alloc((size_t)N_NODES * D_OUT * 2);

    hipMemsetAsync(gcnt, 0, (size_t)NBUK * 4, stream);

    part_kernel<<<NPB, 256, 0, stream>>>(src, dst, gcnt, gbuk);
    sort_kernel<<<NBUK, 256, 0, stream>>>(gcnt, gbuk, sdst, deg);
    convw_kernel<<<(4 * 512 * 64 + 256 * 64 + 255) / 256, 256, 0, stream>>>(W1, W2, Bt1, Bt2);

    gemm1_kernel<<<(N_NODES + 127) / 128, 512, 0, stream>>>(X, Bt1, t1);
    agg1_kernel<<<AGB, 256, 0, stream>>>(t1, deg, sdst, h);
    gemm2_kernel<<<(N_NODES + 63) / 64, 256, 0, stream>>>(h, Bt2, t2);
    agg2_kernel<<<N_NODES / 4, 256, 0, stream>>>(t2, deg, sdst, (float*)d_out);
}

// Round 9
// 414.489 us; speedup vs baseline: 1.6120x; 1.6120x over previous
//
#include <hip/hip_runtime.h>
#include <hip/hip_bf16.h>
#include <stdint.h>

#define N_NODES 50000
#define N_EDGES 1600000
#define D_IN    512
#define D_H1    256   // 4 heads * 64 concat
#define D_OUT   64

#define NBUK    196   // coarse buckets: src>>8 (256 nodes each)
#define MAXB    9216  // per-bucket region capacity (mean 8163, +11 sigma)
#define EPB     4096  // edges per partition block
#define NPB     391   // ceil(N_EDGES / EPB)
#define SLOT    96    // per-node list stride (max degree ~58 for Poisson(32))

#define RSH     12    // dst range = dst>>12 (4096 rows = 2 MB t1 slice, fits per-XCD L2)
#define RR      13    // ceil(50000/4096); stored in 16 slots per node

typedef __attribute__((ext_vector_type(8))) short  short8;   // 8 bf16 = 4 VGPRs (MFMA A/B frag)
typedef __attribute__((ext_vector_type(4))) float  f32x4;    // MFMA C/D frag
typedef __attribute__((ext_vector_type(4))) unsigned int u32x4;
typedef __attribute__((ext_vector_type(2))) unsigned int u32x2;

static __device__ __forceinline__ unsigned short f2bf(float f) {
    union { float f; unsigned int u; } c; c.f = f;
    unsigned int u = c.u;
    return (unsigned short)((u + 0x7FFFu + ((u >> 16) & 1u)) >> 16);  // RNE
}
static __device__ __forceinline__ float bf2f(unsigned short b) {
    union { unsigned int u; float f; } c; c.u = ((unsigned int)b) << 16;
    return c.f;
}
static __device__ __forceinline__ float bflo(unsigned int v) { return bf2f((unsigned short)(v & 0xffffu)); }
static __device__ __forceinline__ float bfhi(unsigned int v) { return bf2f((unsigned short)(v >> 16)); }

// ---------------- phase 1: partition edges into 196 coarse buckets ----------------
// All global writes are run-contiguous (LDS-staged): ~11 MB of line traffic vs the
// ~102 MB a naive per-edge random scatter costs (R5/R6 measured).

__global__ __launch_bounds__(256) void part_kernel(const int* __restrict__ src,
                                                   const int* __restrict__ dst,
                                                   int* __restrict__ gcnt,
                                                   unsigned int* __restrict__ gbuk) {
    __shared__ int hist[NBUK];
    __shared__ int lofs[NBUK];          // exclusive offsets in sorted[]
    __shared__ int gbase[NBUK];         // this block's reservation in bucket region
    __shared__ int sbuf[256];
    __shared__ unsigned int sorted[EPB];
    __shared__ unsigned char bid[EPB];

    const int t  = threadIdx.x;
    const int e0 = blockIdx.x * EPB;
    int ec = N_EDGES - e0; if (ec > EPB) ec = EPB;

    for (int i = t; i < NBUK; i += 256) hist[i] = 0;
    __syncthreads();

    unsigned int rec[16];
    int bb[16], idx[16];
#pragma unroll
    for (int j = 0; j < 16; ++j) {
        int i = j * 256 + t;
        if (i < ec) {
            int s = src[e0 + i], d = dst[e0 + i];
            int b = s >> 8;
            rec[j] = ((unsigned int)(s & 255) << 16) | (unsigned int)d;
            bb[j]  = b;
            idx[j] = atomicAdd(&hist[b], 1);
        } else bb[j] = -1;
    }
    __syncthreads();

    // inclusive scan of hist over 256 slots (entries >= NBUK are 0)
    int v = (t < NBUK) ? hist[t] : 0;
    sbuf[t] = v;
    __syncthreads();
#pragma unroll
    for (int off = 1; off < 256; off <<= 1) {
        int x = (t >= off) ? sbuf[t - off] : 0;
        __syncthreads();
        sbuf[t] += x;
        __syncthreads();
    }
    if (t < NBUK) {
        lofs[t]  = sbuf[t] - v;                 // exclusive
        gbase[t] = atomicAdd(&gcnt[t], v);      // one global atomic per bucket per block
    }
    __syncthreads();

#pragma unroll
    for (int j = 0; j < 16; ++j) {
        if (bb[j] >= 0) {
            int p = lofs[bb[j]] + idx[j];
            sorted[p] = rec[j];
            bid[p] = (unsigned char)bb[j];
        }
    }
    __syncthreads();

    for (int i = t; i < ec; i += 256) {
        int b = bid[i];
        int p = gbase[b] + (i - lofs[b]);
        gbuk[(size_t)b * MAXB + p] = sorted[i];
    }
}

// ---------------- phase 2: per-bucket counting sort by (src, dst-range) ----------------
// 4096 LDS counters = 256 nodes x 16 ranges. Lists come out range-ordered and the
// per-node per-range counts (cnt16) fall out for free -> branch-free phased agg1.

__global__ __launch_bounds__(256) void sort_kernel(const int* __restrict__ gcnt,
                                                   const unsigned int* __restrict__ gbuk,
                                                   unsigned short* __restrict__ sdst,
                                                   int* __restrict__ deg,
                                                   unsigned short* __restrict__ cnt16) {
    __shared__ int hist2[256 * 16];     // 16 KB: [local_src][range]
    __shared__ int nbase[256];
    __shared__ int sbuf[256];
    __shared__ unsigned short list[MAXB];

    const int t = threadIdx.x;
    const int b = blockIdx.x;
    const int cnt = gcnt[b];
    const unsigned int* buk = gbuk + (size_t)b * MAXB;

#pragma unroll
    for (int j = 0; j < 16; ++j) hist2[j * 256 + t] = 0;
    __syncthreads();

    for (int i = t; i < cnt; i += 256) {
        unsigned int r = buk[i];
        int key2 = (int)((r >> 16) << 4) | (int)((r & 0xffffu) >> RSH);
        atomicAdd(&hist2[key2], 1);
    }
    __syncthreads();

    // thread t owns node t's 16 counters: serial prefix + save counts
    int cr[16];
    int tot = 0;
#pragma unroll
    for (int r = 0; r < 16; ++r) { cr[r] = hist2[t * 16 + r]; tot += cr[r]; }

    // block scan of node totals
    sbuf[t] = tot;
    __syncthreads();
#pragma unroll
    for (int off = 1; off < 256; off <<= 1) {
        int x = (t >= off) ? sbuf[t - off] : 0;
        __syncthreads();
        sbuf[t] += x;
        __syncthreads();
    }
    int base = sbuf[t] - tot;           // exclusive node base within bucket
    nbase[t] = base;

    const int n = b * 256 + t;
    {
        int run = base;
#pragma unroll
        for (int r = 0; r < 16; ++r) {  // convert to cursors (exclusive per key2)
            hist2[t * 16 + r] = run;
            run += cr[r];
        }
    }
    if (n < N_NODES) {
        deg[n] = tot;
        unsigned short* cp = cnt16 + (size_t)n * 16;
#pragma unroll
        for (int r = 0; r < 16; ++r) cp[r] = (unsigned short)cr[r];
    }
    __syncthreads();

    for (int i = t; i < cnt; i += 256) {
        unsigned int r = buk[i];
        int key2 = (int)((r >> 16) << 4) | (int)((r & 0xffffu) >> RSH);
        int p = atomicAdd(&hist2[key2], 1);
        list[p] = (unsigned short)(r & 0xffffu);
    }
    __syncthreads();

    if (n < N_NODES && tot > 0) {
        int beg = nbase[t];
        unsigned short* out = sdst + (size_t)n * SLOT;
        for (int j = 0; j < tot; ++j) out[j] = list[beg + j];
    }
}

// ---------------- weight repack (fused, fp32 -> bf16, B transposed: [n][k]) ----------------

__global__ void convw_kernel(const float* __restrict__ W1, const float* __restrict__ W2,
                             unsigned short* __restrict__ Bt1, unsigned short* __restrict__ Bt2) {
    int i = blockIdx.x * 256 + threadIdx.x;
    if (i < 4 * 512 * 64) {                 // W1[h][k][j] -> Bt1[(h*64+j)][k]
        int h = i >> 15;
        int k = (i >> 6) & 511;
        int j = i & 63;
        Bt1[(h * 64 + j) * 512 + k] = f2bf(W1[i]);
    } else {
        int r = i - 4 * 512 * 64;           // W2[k][n] -> Bt2[n][k]
        if (r < 256 * 64) {
            int k = r >> 6;
            int n = r & 63;
            Bt2[n * 256 + k] = f2bf(W2[r]);
        }
    }
}

// ---------------- GEMM1: t1[M][256] = X[M][512](fp32, staged->bf16) @ Bt1[256][512]^T ----------------
// BM=128, BN=256 (A read once), block=512 (8 waves 2x4), wave tile 64x64, BK=32.

__global__ __launch_bounds__(512) void gemm1_kernel(const float* __restrict__ A,
                                                    const unsigned short* __restrict__ Bt,
                                                    unsigned short* __restrict__ C) {
    constexpr int BM = 128, BN = 256, BK = 32, LDK = 40, K = D_IN, M = N_NODES, N = D_H1;
    __shared__ unsigned short As[BM * LDK];   // 10.0 KB
    __shared__ unsigned short Bs[BN * LDK];   // 20.0 KB

    const int tid  = threadIdx.x;
    const int lane = tid & 63;
    const int w    = tid >> 6;
    const int wm   = (w >> 2) * 64;
    const int wn   = (w & 3) * 64;
    const int quad = lane >> 4;
    const int l15  = lane & 15;
    const int bm   = blockIdx.x;

    f32x4 acc[4][4];
#pragma unroll
    for (int mi = 0; mi < 4; ++mi)
#pragma unroll
        for (int ni = 0; ni < 4; ++ni)
            acc[mi][ni] = (f32x4){0.f, 0.f, 0.f, 0.f};

    const int r0 = tid >> 2;      // 0..127
    const int f8 = tid & 3;       // 8-elem chunk within a 32-col row

    for (int k0 = 0; k0 < K; k0 += BK) {
        {   // stage A (128 x 32 fp32 -> bf16), 8 floats per thread
            int grow = bm * BM + r0;
            if (grow >= M) grow = M - 1;
            const float* ap = A + (size_t)grow * K + k0 + f8 * 8;
            f32x4 v0 = *(const f32x4*)ap;
            f32x4 v1 = *(const f32x4*)(ap + 4);
            u32x4 pk;
            pk[0] = (unsigned int)f2bf(v0[0]) | ((unsigned int)f2bf(v0[1]) << 16);
            pk[1] = (unsigned int)f2bf(v0[2]) | ((unsigned int)f2bf(v0[3]) << 16);
            pk[2] = (unsigned int)f2bf(v1[0]) | ((unsigned int)f2bf(v1[1]) << 16);
            pk[3] = (unsigned int)f2bf(v1[2]) | ((unsigned int)f2bf(v1[3]) << 16);
            *(u32x4*)&As[r0 * LDK + f8 * 8] = pk;
        }
        {   // stage B (256 x 32 bf16), two u32x4 per thread
#pragma unroll
            for (int p = 0; p < 2; ++p) {
                int row = p * 128 + r0;
                u32x4 v = *(const u32x4*)(Bt + (size_t)row * K + k0 + f8 * 8);
                *(u32x4*)&Bs[row * LDK + f8 * 8] = v;
            }
        }
        __syncthreads();

        short8 af[4], bfr[4];
#pragma unroll
        for (int mi = 0; mi < 4; ++mi)
            af[mi] = *(const short8*)&As[(wm + mi * 16 + l15) * LDK + quad * 8];
#pragma unroll
        for (int ni = 0; ni < 4; ++ni)
            bfr[ni] = *(const short8*)&Bs[(wn + ni * 16 + l15) * LDK + quad * 8];
#pragma unroll
        for (int mi = 0; mi < 4; ++mi)
#pragma unroll
            for (int ni = 0; ni < 4; ++ni)
                acc[mi][ni] = __builtin_amdgcn_mfma_f32_16x16x32_bf16(af[mi], bfr[ni], acc[mi][ni], 0, 0, 0);
        __syncthreads();
    }

#pragma unroll
    for (int mi = 0; mi < 4; ++mi) {
        int row0 = bm * BM + wm + mi * 16 + quad * 4;
#pragma unroll
        for (int ni = 0; ni < 4; ++ni) {
            int col = wn + ni * 16 + l15;
#pragma unroll
            for (int r = 0; r < 4; ++r) {
                int row = row0 + r;
                if (row < M) C[(size_t)row * N + col] = f2bf(acc[mi][ni][r]);
            }
        }
    }
}

// ---------------- GEMM2: t2[M][64] = h[M][256](bf16) @ Bt2[64][256]^T ----------------

__global__ __launch_bounds__(256) void gemm2_kernel(const unsigned short* __restrict__ A,
                                                    const unsigned short* __restrict__ Bt,
                                                    unsigned short* __restrict__ C) {
    constexpr int BM = 64, BN = 64, BK = 32, LDK = 40, K = D_H1, M = N_NODES, N = D_OUT;
    __shared__ unsigned short As[BM * LDK];
    __shared__ unsigned short Bs[BN * LDK];

    const int tid  = threadIdx.x;
    const int lane = tid & 63;
    const int w    = tid >> 6;
    const int wm   = (w >> 1) * 32;
    const int wn   = (w & 1) * 32;
    const int quad = lane >> 4;
    const int l15  = lane & 15;
    const int bm   = blockIdx.x;

    f32x4 acc[2][2];
#pragma unroll
    for (int mi = 0; mi < 2; ++mi)
#pragma unroll
        for (int ni = 0; ni < 2; ++ni)
            acc[mi][ni] = (f32x4){0.f, 0.f, 0.f, 0.f};

    for (int k0 = 0; k0 < K; k0 += BK) {
        {
            int f8 = tid & 3;
            int r0 = tid >> 2;
            int grow = bm * BM + r0;
            if (grow >= M) grow = M - 1;
            u32x4 v = *(const u32x4*)(A + (size_t)grow * K + k0 + f8 * 8);
            *(u32x4*)&As[r0 * LDK + f8 * 8] = v;
        }
        {
            int f8 = tid & 3;
            int r0 = tid >> 2;
            u32x4 v = *(const u32x4*)(Bt + (size_t)r0 * K + k0 + f8 * 8);
            *(u32x4*)&Bs[r0 * LDK + f8 * 8] = v;
        }
        __syncthreads();

        short8 af[2], bfr[2];
#pragma unroll
        for (int mi = 0; mi < 2; ++mi)
            af[mi] = *(const short8*)&As[(wm + mi * 16 + l15) * LDK + quad * 8];
#pragma unroll
        for (int ni = 0; ni < 2; ++ni)
            bfr[ni] = *(const short8*)&Bs[(wn + ni * 16 + l15) * LDK + quad * 8];
#pragma unroll
        for (int mi = 0; mi < 2; ++mi)
#pragma unroll
            for (int ni = 0; ni < 2; ++ni)
                acc[mi][ni] = __builtin_amdgcn_mfma_f32_16x16x32_bf16(af[mi], bfr[ni], acc[mi][ni], 0, 0, 0);
        __syncthreads();
    }

#pragma unroll
    for (int mi = 0; mi < 2; ++mi) {
        int row0 = bm * BM + wm + mi * 16 + quad * 4;
#pragma unroll
        for (int ni = 0; ni < 2; ++ni) {
            int col = wn + ni * 16 + l15;
#pragma unroll
            for (int r = 0; r < 4; ++r) {
                int row = row0 + r;
                if (row < M) C[(size_t)row * N + col] = f2bf(acc[mi][ni][r]);
            }
        }
    }
}

// ---------------- aggregation 1: phased range sweep, branch-free segments ----------------
// R7 execution (wave per node, half-wave x 16B = 512B row, unrolled multi-edge loop)
// + R4/R8 locality (outer loop over 13 dst-ranges of 2 MB; segment lengths known in
// advance from cnt16 so gathers issue without data-dependent branches).

__global__ __launch_bounds__(256) void agg1_kernel(const unsigned short* __restrict__ t,
                                                   const unsigned short* __restrict__ cnt16,
                                                   const unsigned short* __restrict__ sdst,
                                                   const int* __restrict__ deg,
                                                   unsigned short* __restrict__ h) {
    int s = __builtin_amdgcn_readfirstlane(blockIdx.x * 4 + (threadIdx.x >> 6));
    int lane = threadIdx.x & 63;
    int sub = lane >> 5;         // which of 2 concurrent edges
    int c   = lane & 31;         // 8 cols per lane: 8c..8c+7
    const unsigned short* el = sdst + (size_t)s * SLOT;
    const unsigned short* base = t + 8 * c;
    const unsigned short* cp = cnt16 + (size_t)s * 16;

    float a[8];
#pragma unroll
    for (int k = 0; k < 8; ++k) a[k] = 0.f;

    int e = 0;
    for (int r = 0; r < RR; ++r) {
        int e_end = e + cp[r];
        for (; e + 4 <= e_end; e += 4) {     // 2 gathers in flight per half-wave
            int i0 = el[e + sub], i1 = el[e + 2 + sub];
            u32x4 v0 = *(const u32x4*)(base + (size_t)i0 * D_H1);
            u32x4 v1 = *(const u32x4*)(base + (size_t)i1 * D_H1);
#pragma unroll
            for (int q = 0; q < 4; ++q) {
                a[2 * q]     += bflo(v0[q]) + bflo(v1[q]);
                a[2 * q + 1] += bfhi(v0[q]) + bfhi(v1[q]);
            }
        }
        if (e + 2 <= e_end) {
            int i0 = el[e + sub];
            u32x4 v = *(const u32x4*)(base + (size_t)i0 * D_H1);
#pragma unroll
            for (int q = 0; q < 4; ++q) {
                a[2 * q]     += bflo(v[q]);
                a[2 * q + 1] += bfhi(v[q]);
            }
            e += 2;
        }
        if (e < e_end) {
            if (sub == 0) {
                int i0 = el[e];
                u32x4 v = *(const u32x4*)(base + (size_t)i0 * D_H1);
#pragma unroll
                for (int q = 0; q < 4; ++q) {
                    a[2 * q]     += bflo(v[q]);
                    a[2 * q + 1] += bfhi(v[q]);
                }
            }
            e = e_end;
        }
        __syncthreads();   // keep the block's 4 waves on the same t1 slice
    }

#pragma unroll
    for (int k = 0; k < 8; ++k) a[k] += __shfl_xor(a[k], 32);

    if (sub == 0) {
        int dg = deg[s];
        float iv = (dg > 0) ? (1.0f / (float)dg) : 0.f;
        u32x4 pk;
#pragma unroll
        for (int q = 0; q < 4; ++q) {
            float m0 = a[2 * q] * iv, m1 = a[2 * q + 1] * iv;
            m0 = (m0 > 0.f) ? m0 : (__expf(m0) - 1.f);
            m1 = (m1 > 0.f) ? m1 : (__expf(m1) - 1.f);
            pk[q] = (unsigned int)f2bf(m0) | ((unsigned int)f2bf(m1) << 16);
        }
        *(u32x4*)&h[(size_t)s * D_H1 + 8 * c] = pk;
    }
}

// ---------------- aggregation 2: one wave per node, quarter-wave x 4 edges ----------------

__global__ __launch_bounds__(256) void agg2_kernel(const unsigned short* __restrict__ t2,
                                                   const int* __restrict__ deg,
                                                   const unsigned short* __restrict__ sdst,
                                                   float* __restrict__ out) {
    int s = __builtin_amdgcn_readfirstlane(blockIdx.x * 4 + (threadIdx.x >> 6));
    int lane = threadIdx.x & 63;
    int sub = lane >> 4;         // which of 4 concurrent edges
    int c   = lane & 15;         // 4 cols per lane: 4c..4c+3
    int end = deg[s];
    const unsigned short* el = sdst + (size_t)s * SLOT;
    const unsigned short* bb = t2 + 4 * c;

    float a0 = 0.f, a1 = 0.f, a2 = 0.f, a3 = 0.f;
    int e = 0;
    for (; e + 8 <= end; e += 8) {
        int i0 = el[e + sub], i1 = el[e + 4 + sub];
        u32x2 v0 = *(const u32x2*)(bb + (size_t)i0 * D_OUT);
        u32x2 v1 = *(const u32x2*)(bb + (size_t)i1 * D_OUT);
        a0 += bflo(v0[0]) + bflo(v1[0]);
        a1 += bfhi(v0[0]) + bfhi(v1[0]);
        a2 += bflo(v0[1]) + bflo(v1[1]);
        a3 += bfhi(v0[1]) + bfhi(v1[1]);
    }
    for (; e + 4 <= end; e += 4) {
        int i0 = el[e + sub];
        u32x2 v = *(const u32x2*)(bb + (size_t)i0 * D_OUT);
        a0 += bflo(v[0]); a1 += bfhi(v[0]); a2 += bflo(v[1]); a3 += bfhi(v[1]);
    }
    int rem = end - e;
    if (sub < rem) {
        int i0 = el[e + sub];
        u32x2 v = *(const u32x2*)(bb + (size_t)i0 * D_OUT);
        a0 += bflo(v[0]); a1 += bfhi(v[0]); a2 += bflo(v[1]); a3 += bfhi(v[1]);
    }
    a0 += __shfl_xor(a0, 16); a1 += __shfl_xor(a1, 16);
    a2 += __shfl_xor(a2, 16); a3 += __shfl_xor(a3, 16);
    a0 += __shfl_xor(a0, 32); a1 += __shfl_xor(a1, 32);
    a2 += __shfl_xor(a2, 32); a3 += __shfl_xor(a3, 32);
    if (sub == 0) {
        float iv = (end > 0) ? (1.0f / (float)end) : 0.f;
        f32x4 r; r[0] = a0 * iv; r[1] = a1 * iv; r[2] = a2 * iv; r[3] = a3 * iv;
        *(f32x4*)(out + (size_t)s * D_OUT + 4 * c) = r;
    }
}

// ---------------- launch ----------------

extern "C" void kernel_launch(void* const* d_in, const int* in_sizes, int n_in,
                              void* d_out, int out_size, void* d_ws, size_t ws_size,
                              hipStream_t stream) {
    const float* X  = (const float*)d_in[0];
    const int*   ei = (const int*)d_in[1];
    const float* W1 = (const float*)d_in[2];
    const float* W2 = (const float*)d_in[3];
    const int* src = ei;             // edge_index[0] = segment ids
    const int* dst = ei + N_EDGES;   // edge_index[1] = gathered neighbors

    char* ws = (char*)d_ws;
    size_t off = 0;
    auto alloc = [&](size_t bytes) {
        off = (off + 255) & ~(size_t)255;
        void* p = ws + off;
        off += bytes;
        return p;
    };
    int*          gcnt = (int*)alloc((size_t)NBUK * 4);
    unsigned int* gbuk = (unsigned int*)alloc((size_t)NBUK * MAXB * 4);
    unsigned short* sdst = (unsigned short*)alloc(((size_t)N_NODES * SLOT + 64) * 2);
    int*          deg  = (int*)alloc((size_t)N_NODES * 4);
    unsigned short* cnt16 = (unsigned short*)alloc((size_t)N_NODES * 16 * 2);
    unsigned short* Bt1 = (unsigned short*)alloc((size_t)D_H1 * D_IN * 2);
    unsigned short* Bt2 = (unsigned short*)alloc((size_t)D_OUT * D_H1 * 2);
    unsigned short* t1  = (unsigned short*)alloc((size_t)N_NODES * D_H1 * 2);
    unsigned short* h   = (unsigned short*)alloc((size_t)N_NODES * D_H1 * 2);
    unsigned short* t2  = (unsigned short*)alloc((size_t)N_NODES * D_OUT * 2);

    hipMemsetAsync(gcnt, 0, (size_t)NBUK * 4, stream);

    part_kernel<<<NPB, 256, 0, stream>>>(src, dst, gcnt, gbuk);
    sort_kernel<<<NBUK, 256, 0, stream>>>(gcnt, gbuk, sdst, deg, cnt16);
    convw_kernel<<<(4 * 512 * 64 + 256 * 64 + 255) / 256, 256, 0, stream>>>(W1, W2, Bt1, Bt2);

    gemm1_kernel<<<(N_NODES + 127) / 128, 512, 0, stream>>>(X, Bt1, t1);
    agg1_kernel<<<N_NODES / 4, 256, 0, stream>>>(t1, cnt16, sdst, deg, h);
    gemm2_kernel<<<(N_NODES + 63) / 64, 256, 0, stream>>>(h, Bt2, t2);
    agg2_kernel<<<N_NODES / 4, 256, 0, stream>>>(t2, deg, sdst, (float*)d_out);
}